// Round 14
// baseline (262.866 us; speedup 1.0000x reference)
//
#include <hip/hip_runtime.h>
#include <hip/hip_bf16.h>
#include <math.h>

#define NN 150000
#define EE 600000
#define GG 5000
#define NI 16
#define EI 8
#define GFD 32
#define HH 64
#define CC 40

#define W2SZ (68 * 1024)   // 68 chunks (64 real + bias@64 + 3 zero) x 64 rows x 16 k, chunk-major
#define EHS 72             // u16 stride of sEHT2 rows (144B: 16B-aligned, 4-way max on b128)
#define FPAD 68
#define NBLK ((NN + 1023) / 1024)

typedef __attribute__((ext_vector_type(8))) short short8v;
typedef __attribute__((ext_vector_type(8))) unsigned short ushort8v;
typedef __attribute__((ext_vector_type(16))) float f32x16;
typedef __attribute__((ext_vector_type(2))) float f32x2;

__device__ __forceinline__ unsigned short f2bf(float f) {
    __hip_bfloat16 h = __float2bfloat16(f);
    return __builtin_bit_cast(unsigned short, h);
}
__device__ __forceinline__ float bf2f(unsigned short u) {
    return __uint_as_float(((unsigned)u) << 16);
}
__device__ __forceinline__ unsigned cvtpk(float lo, float hi) {
    unsigned r;
    asm("v_cvt_pk_bf16_f32 %0, %1, %2" : "=v"(r) : "v"(lo), "v"(hi));
    return r;
}
__device__ __forceinline__ f32x2 pkmul(f32x2 a, f32x2 b) {
    f32x2 p;
    asm("v_pk_mul_f32 %0, %1, %2" : "=v"(p) : "v"(a), "v"(b));
    return p;
}
__device__ __forceinline__ short8v zfrag(float eh, const f32x2 (&xs2)[4]) {
    f32x2 ehp; ehp[0] = eh; ehp[1] = eh;
    union { short8v v; unsigned u[4]; } A;
    #pragma unroll
    for (int q = 0; q < 4; ++q) {
        f32x2 p = pkmul(ehp, xs2[q]);
        A.u[q] = cvtpk(p[0], p[1]);
    }
    return A.v;
}
__device__ __forceinline__ short8v xfrag(const f32x2 (&xs2)[4]) {
    union { short8v v; unsigned u[4]; } A;
    #pragma unroll
    for (int q = 0; q < 4; ++q)
        A.u[q] = cvtpk(xs2[q][0], xs2[q][1]);
    return A.v;
}

// ---------------- K0: prep bf16 weight views + zero cursor ----------------
__global__ void k0_prep(const float* __restrict__ W_e2, const float* __restrict__ b_e2,
                        const float* __restrict__ W_fc1, const float* __restrict__ W_np,
                        const float* __restrict__ W_e1,
                        unsigned short* __restrict__ W2c,
                        unsigned short* __restrict__ W1aT,
                        unsigned short* __restrict__ W_npT,
                        unsigned short* __restrict__ W1e,
                        int* __restrict__ cursor)
{
    int idx = blockIdx.x * 256 + threadIdx.x;
    if (idx < W2SZ) {
        int c = idx >> 10, rem = idx & 1023;
        int r = rem >> 4, kk = rem & 15;
        float v = 0.f;
        if (c < 64)       v = W_e2[c * 1024 + kk * 64 + r];
        else if (c == 64) v = b_e2[kk * 64 + r];
        W2c[idx] = f2bf(v);
    } else if (idx < W2SZ + 4096) {
        int i = idx - W2SZ;
        int h = i >> 6, k = i & 63;
        W1aT[i] = f2bf(W_fc1[k * 64 + h]);
    } else if (idx < W2SZ + 8192) {
        int i = idx - W2SZ - 4096;
        int c = i >> 6, h = i & 63;
        W_npT[i] = f2bf(c < CC ? W_np[h * CC + c] : 0.f);
    } else if (idx < W2SZ + 8704) {
        int i = idx - W2SZ - 8192;   // W1e[col][q] = W_e1[q][col]
        int col = i >> 3, q = i & 7;
        W1e[i] = f2bf(W_e1[q * 64 + col]);
    } else if (idx < W2SZ + 8704 + NN) {
        cursor[idx - W2SZ - 8704] = 0;
    }
}

// ---------------- kE_local: local rank within dst + counts ----------------
__global__ void kE_local(const int* __restrict__ ei, int* __restrict__ cursor,
                         int* __restrict__ rank)
{
    int e = blockIdx.x * 256 + threadIdx.x;
    if (e < EE) rank[e] = atomicAdd(&cursor[ei[EE + e]], 1);
}

// ---------------- scan of counts -> base (block-local; consumers add bsum[i>>10]) ----------------
__global__ void kB_scan1(const int* __restrict__ cnt, int* __restrict__ base,
                         int* __restrict__ bsum)
{
    __shared__ int sS[256];
    int b = blockIdx.x, t = threadIdx.x;
    int i0 = b * 1024 + t * 4;
    int v0 = (i0 + 0 < NN) ? cnt[i0 + 0] : 0;
    int v1 = (i0 + 1 < NN) ? cnt[i0 + 1] : 0;
    int v2 = (i0 + 2 < NN) ? cnt[i0 + 2] : 0;
    int v3 = (i0 + 3 < NN) ? cnt[i0 + 3] : 0;
    int tot = v0 + v1 + v2 + v3;
    sS[t] = tot;
    __syncthreads();
    int acc = tot;
    for (int off = 1; off < 256; off <<= 1) {
        int xv = (t >= off) ? sS[t - off] : 0;
        __syncthreads();
        acc += xv;
        sS[t] = acc;
        __syncthreads();
    }
    int run = acc - tot;
    if (i0 + 0 < NN) base[i0 + 0] = run; run += v0;
    if (i0 + 1 < NN) base[i0 + 1] = run; run += v1;
    if (i0 + 2 < NN) base[i0 + 2] = run; run += v2;
    if (i0 + 3 < NN) base[i0 + 3] = run;
    if (t == 255) bsum[b] = acc;
}

__global__ void kC_scan2(int* __restrict__ bsum)
{
    __shared__ int sS[256];
    int t = threadIdx.x;
    int v = (t < NBLK) ? bsum[t] : 0;
    sS[t] = v;
    __syncthreads();
    int acc = v;
    for (int off = 1; off < 256; off <<= 1) {
        int xv = (t >= off) ? sS[t - off] : 0;
        __syncthreads();
        acc += xv;
        sS[t] = acc;
        __syncthreads();
    }
    if (t < NBLK) bsum[t] = acc - v;   // exclusive
}

// ---------------- K1: M=64 x N=32 wave tiles (2 edge-groups x 2 N-halves per block) ----------------
template<bool TWOPHASE>
__global__ __launch_bounds__(256, 5) void k1_mfma(
    const float* __restrict__ x, const int* __restrict__ ei,
    const float* __restrict__ ea,
    const unsigned short* __restrict__ W1e, const float* __restrict__ b_e1,
    const unsigned short* __restrict__ W2c,
    const int* __restrict__ rank, const int* __restrict__ base,
    const int* __restrict__ bsum,
    unsigned short* __restrict__ msgb, float* __restrict__ agg)
{
    __shared__ unsigned short sEHT2[128][EHS];   // [edge][k] bf16, transposed
    __shared__ int sIdx[128];

    const int t = threadIdx.x;
    const long long eb = (long long)blockIdx.x * 128;

    const int lane = t & 63;
    const int w = t >> 6;
    const int mr = lane & 31;
    const int half = lane >> 5;
    const int egrp = w >> 1;        // edge group (0,1): 64 edges each
    const int nhalf = w & 1;        // N half: cols nhalf*32 .. +31
    const int mlp_eb = w * 32;      // wave's 32 edges for the MLP phase

    if (t < 128) {
        long long ge = eb + t;
        if (ge < EE) {
            int d = ei[EE + ge];
            sIdx[t] = TWOPHASE ? (base[d] + bsum[d >> 10] + rank[ge]) : d;
        } else {
            sIdx[t] = -1;
        }
    }

    // ---- edge MLP layer 1 via MFMA (wave's own 32 edges) -> sEHT2 transposed ----
    {
        short8v bW0, bW1;
        if (half == 0) {
            bW0 = *(const short8v*)(W1e + (size_t)mr * 8);
            bW1 = *(const short8v*)(W1e + (size_t)(32 + mr) * 8);
        } else {
            #pragma unroll
            for (int q = 0; q < 8; ++q) { bW0[q] = 0; bW1[q] = 0; }
        }
        float bias0 = b_e1[mr];
        float bias1 = b_e1[32 + mr];
        long long ge = eb + mlp_eb + mr;
        short8v a;
        if (half == 0 && ge < EE) {
            const float4* eap = (const float4*)(ea + ge * EI);
            float4 u0 = eap[0], u1 = eap[1];
            union { short8v v; unsigned u[4]; } A;
            A.u[0] = cvtpk(u0.x, u0.y); A.u[1] = cvtpk(u0.z, u0.w);
            A.u[2] = cvtpk(u1.x, u1.y); A.u[3] = cvtpk(u1.z, u1.w);
            a = A.v;
        } else {
            #pragma unroll
            for (int q = 0; q < 8; ++q) a[q] = 0;
        }
        #pragma unroll
        for (int n = 0; n < 2; ++n) {
            f32x16 c_;
            #pragma unroll
            for (int r = 0; r < 16; ++r) c_[r] = 0.f;
            c_ = __builtin_amdgcn_mfma_f32_32x32x16_bf16(a, n ? bW1 : bW0, c_, 0, 0, 0);
            int kcol = n * 32 + mr;
            float bias = n ? bias1 : bias0;
            #pragma unroll
            for (int r = 0; r < 16; ++r) {
                int row = (r & 3) + 8 * (r >> 2) + 4 * half;
                sEHT2[mlp_eb + row][kcol] = f2bf(fmaxf(c_[r] + bias, 0.f));
            }
        }
    }

    // ---- per-lane xs gather (2 edges: e0 = egrp*64+mr, e1 = +32) ----
    f32x2 xs0[4], xs1[4];
    {
        long long g0 = eb + egrp * 64 + mr;
        long long g1 = g0 + 32;
        if (g0 < EE) {
            int s0 = ei[g0];
            const float4* xp = (const float4*)(x + (size_t)s0 * NI + half * 8);
            float4 u0 = xp[0], u1 = xp[1];
            xs0[0][0]=u0.x; xs0[0][1]=u0.y; xs0[1][0]=u0.z; xs0[1][1]=u0.w;
            xs0[2][0]=u1.x; xs0[2][1]=u1.y; xs0[3][0]=u1.z; xs0[3][1]=u1.w;
        } else {
            #pragma unroll
            for (int q = 0; q < 4; ++q) { xs0[q][0] = 0.f; xs0[q][1] = 0.f; }
        }
        if (g1 < EE) {
            int s1 = ei[g1];
            const float4* xp = (const float4*)(x + (size_t)s1 * NI + half * 8);
            float4 u0 = xp[0], u1 = xp[1];
            xs1[0][0]=u0.x; xs1[0][1]=u0.y; xs1[1][0]=u0.z; xs1[1][1]=u0.w;
            xs1[2][0]=u1.x; xs1[2][1]=u1.y; xs1[3][0]=u1.z; xs1[3][1]=u1.w;
        } else {
            #pragma unroll
            for (int q = 0; q < 4; ++q) { xs1[q][0] = 0.f; xs1[q][1] = 0.f; }
        }
    }
    __syncthreads();

    f32x16 acc0, acc1;    // edge-subtile 0 / 1, cols nhalf*32..+31
    #pragma unroll
    for (int r = 0; r < 16; ++r) { acc0[r] = 0.f; acc1[r] = 0.f; }

    // chunk-major B: wave reads its 1KB N-half per chunk
    const unsigned short* Bq = W2c + nhalf * 512 + mr * 16 + half * 8;

    short8v bA = *(const short8v*)(Bq);
    short8v bB = *(const short8v*)(Bq + 1024);

    const unsigned short* ehp0 = &sEHT2[egrp * 64 + mr][0];
    const unsigned short* ehp1 = ehp0 + 32 * EHS;

    #pragma unroll 1
    for (int cb = 0; cb < 64; cb += 8) {
        ushort8v eh0 = *(const ushort8v*)(ehp0 + cb);
        ushort8v eh1 = *(const ushort8v*)(ehp1 + cb);
        #pragma unroll
        for (int j = 0; j < 8; j += 2) {
            int c = cb + j;
            {
                short8v nx = *(const short8v*)(Bq + (c + 2) * 1024);
                short8v a0 = zfrag(bf2f(eh0[j]), xs0);
                short8v a1 = zfrag(bf2f(eh1[j]), xs1);
                __builtin_amdgcn_s_setprio(1);
                acc0 = __builtin_amdgcn_mfma_f32_32x32x16_bf16(a0, bA, acc0, 0, 0, 0);
                acc1 = __builtin_amdgcn_mfma_f32_32x32x16_bf16(a1, bA, acc1, 0, 0, 0);
                __builtin_amdgcn_s_setprio(0);
                bA = nx;
            }
            {
                short8v nx = *(const short8v*)(Bq + (c + 3) * 1024);
                short8v a0 = zfrag(bf2f(eh0[j + 1]), xs0);
                short8v a1 = zfrag(bf2f(eh1[j + 1]), xs1);
                __builtin_amdgcn_s_setprio(1);
                acc0 = __builtin_amdgcn_mfma_f32_32x32x16_bf16(a0, bB, acc0, 0, 0, 0);
                acc1 = __builtin_amdgcn_mfma_f32_32x32x16_bf16(a1, bB, acc1, 0, 0, 0);
                __builtin_amdgcn_s_setprio(0);
                bB = nx;
            }
        }
    }
    // bias chunk c=64: eh = 1 -> A = bf16(xs); B in bA (prefetched at c=62)
    {
        short8v a0 = xfrag(xs0);
        short8v a1 = xfrag(xs1);
        __builtin_amdgcn_s_setprio(1);
        acc0 = __builtin_amdgcn_mfma_f32_32x32x16_bf16(a0, bA, acc0, 0, 0, 0);
        acc1 = __builtin_amdgcn_mfma_f32_32x32x16_bf16(a1, bA, acc1, 0, 0, 0);
        __builtin_amdgcn_s_setprio(0);
    }

    // ---- epilogue: bf16 u16 stores (wave owns cols nhalf*32..+31) ----
    #pragma unroll
    for (int r = 0; r < 16; ++r) {
        int row = (r & 3) + 8 * (r >> 2) + 4 * half;
        int i0 = sIdx[egrp * 64 + row];
        int i1 = sIdx[egrp * 64 + 32 + row];
        if (TWOPHASE) {
            if (i0 >= 0) msgb[(size_t)i0 * 64 + nhalf * 32 + mr] = f2bf(acc0[r]);
            if (i1 >= 0) msgb[(size_t)i1 * 64 + nhalf * 32 + mr] = f2bf(acc1[r]);
        } else {
            if (i0 >= 0) atomicAdd(&agg[(size_t)i0 * 64 + nhalf * 32 + mr], acc0[r]);
            if (i1 >= 0) atomicAdd(&agg[(size_t)i1 * 64 + nhalf * 32 + mr], acc1[r]);
        }
    }
}

// ---------------- K2 (two-phase): stream-reduce bf16 msgb + mean + root + relu + gate ----------------
__global__ __launch_bounds__(256) void k2_red(
    const unsigned short* __restrict__ msgb, const int* __restrict__ base,
    const int* __restrict__ bsum,
    const float* __restrict__ x, const float* __restrict__ root,
    const float* __restrict__ conv_bias,
    unsigned short* __restrict__ hn16,
    const float* __restrict__ Wg, const float* __restrict__ bg,
    float* __restrict__ gate)
{
    __shared__ float sroot[16][64];
    int t = threadIdx.x;
    #pragma unroll
    for (int q = 0; q < 4; ++q) {
        int i = q * 256 + t;
        sroot[i >> 6][i & 63] = root[i];
    }
    __syncthreads();

    const unsigned* msgu = (const unsigned*)msgb;
    int n = blockIdx.x * 4 + (t >> 6);
    int l = t & 63;
    int m = l & 31, so = l >> 5;
    int s = base[n] + bsum[n >> 10];
    int e = (n == NN - 1) ? EE : base[n + 1] + bsum[(n + 1) >> 10];

    // u32 read = cols (2m, 2m+1) of slot sl
    float alo = 0.f, ahi = 0.f;
    int sl = s + so;
    for (; sl + 2 < e; sl += 4) {
        unsigned u0 = msgu[(size_t)sl * 32 + m];
        unsigned u1 = msgu[(size_t)(sl + 2) * 32 + m];
        alo += __uint_as_float(u0 << 16) + __uint_as_float(u1 << 16);
        ahi += __uint_as_float(u0 & 0xFFFF0000u) + __uint_as_float(u1 & 0xFFFF0000u);
    }
    if (sl < e) {
        unsigned u = msgu[(size_t)sl * 32 + m];
        alo += __uint_as_float(u << 16);
        ahi += __uint_as_float(u & 0xFFFF0000u);
    }
    alo += __shfl_xor(alo, 32);
    ahi += __shfl_xor(ahi, 32);
    // col l lives at lane l>>1: parity picks lo/hi
    float alo_s = __shfl(alo, l >> 1);
    float ahi_s = __shfl(ahi, l >> 1);
    float acc = (l & 1) ? ahi_s : alo_s;

    float inv = 1.0f / fmaxf((float)(e - s), 1.0f);
    float v = acc * inv + conv_bias[l];
    float xv = (l < 16) ? x[(size_t)n * NI + l] : 0.f;
    #pragma unroll
    for (int i = 0; i < 16; ++i)
        v = fmaf(__shfl(xv, i), sroot[i][l], v);
    v = fmaxf(v, 0.f);
    hn16[(size_t)n * 64 + l] = f2bf(v);

    float gv = v * Wg[l];
    #pragma unroll
    for (int off = 32; off; off >>= 1) gv += __shfl_xor(gv, off);
    if (l == 0) gate[n] = gv + bg[0];
}

// ---------------- K2 (fallback): mean + root + relu over agg ----------------
__global__ __launch_bounds__(256) void k2_node(
    const float* __restrict__ agg, const int* __restrict__ base,
    const int* __restrict__ bsum,
    const float* __restrict__ x, const float* __restrict__ root,
    const float* __restrict__ conv_bias,
    unsigned short* __restrict__ hn16,
    const float* __restrict__ Wg, const float* __restrict__ bg,
    float* __restrict__ gate)
{
    int t = threadIdx.x;
    int n = blockIdx.x * 4 + (t >> 6);
    int h = t & 63;
    int s = base[n] + bsum[n >> 10];
    int e = (n == NN - 1) ? EE : base[n + 1] + bsum[(n + 1) >> 10];
    float inv = 1.0f / fmaxf((float)(e - s), 1.0f);
    float v = agg[(size_t)n * 64 + h] * inv + conv_bias[h];
    const float* xp = x + (size_t)n * NI;
    #pragma unroll
    for (int i = 0; i < NI; ++i) v += xp[i] * root[i * 64 + h];
    v = fmaxf(v, 0.f);
    hn16[(size_t)n * 64 + h] = f2bf(v);
    float gv = v * Wg[h];
    #pragma unroll
    for (int off = 32; off; off >>= 1) gv += __shfl_xor(gv, off);
    if (h == 0) gate[n] = gv + bg[0];
}

// ---------------- K3: per-graph pooling + pg/sg precompute ----------------
__device__ __forceinline__ int lbound(const int* __restrict__ b, int v) {
    int lo = 0, hi = NN;
    while (lo < hi) { int mid = (lo + hi) >> 1; if (b[mid] < v) lo = mid + 1; else hi = mid; }
    return lo;
}

__global__ __launch_bounds__(64) void k3_pool(
    const float* __restrict__ gate, const int* __restrict__ batch,
    const unsigned short* __restrict__ hn16, const float* __restrict__ pocket,
    const float* __restrict__ W_fc1, const float* __restrict__ b_fc1,
    const float* __restrict__ W_sp, const float* __restrict__ b_sp,
    float* __restrict__ pg, float* __restrict__ sg)
{
    int g = blockIdx.x;
    int lane = threadIdx.x;
    int s = lbound(batch, g);
    int e = lbound(batch, g + 1);

    float gcv = 0.f;
    if (e > s) {
        float m = -INFINITY;
        for (int n = s + lane; n < e; n += 64) m = fmaxf(m, gate[n]);
        #pragma unroll
        for (int off = 32; off; off >>= 1) m = fmaxf(m, __shfl_xor(m, off));
        float acc = 0.f, den = 0.f;
        int n = s;
        for (; n + 2 <= e; n += 2) {
            float e0 = expf(gate[n] - m);
            float e1 = expf(gate[n + 1] - m);
            float h0 = bf2f(hn16[(size_t)n * 64 + lane]);
            float h1 = bf2f(hn16[(size_t)(n + 1) * 64 + lane]);
            den += e0 + e1;
            acc = fmaf(e0, h0, acc);
            acc = fmaf(e1, h1, acc);
        }
        if (n < e) {
            float ev = expf(gate[n] - m);
            den += ev;
            acc = fmaf(ev, bf2f(hn16[(size_t)n * 64 + lane]), acc);
        }
        gcv = acc / den;
    }

    float sv = gcv * W_sp[lane];
    #pragma unroll
    for (int off = 32; off; off >>= 1) sv += __shfl_xor(sv, off);
    if (lane == 0) sg[g] = 1.f / (1.f + expf(-(sv + b_sp[0])));

    float pk = (lane < GFD) ? pocket[(size_t)g * GFD + lane] : 0.f;
    float pgv = b_fc1[lane];
    #pragma unroll 8
    for (int kk = 0; kk < 64; ++kk)
        pgv = fmaf(__shfl(gcv, kk), W_fc1[(64 + kk) * 64 + lane], pgv);
    #pragma unroll 8
    for (int kk = 0; kk < 32; ++kk)
        pgv = fmaf(__shfl(pk, kk), W_fc1[(128 + kk) * 64 + lane], pgv);
    pg[(size_t)g * 64 + lane] = pgv;
}

// ---------------- K4: MFMA head ----------------
__global__ __launch_bounds__(256, 4) void k4_mfma(
    const unsigned short* __restrict__ hn16, const int* __restrict__ batch,
    const float* __restrict__ pg, const float* __restrict__ sg,
    const unsigned short* __restrict__ W1aT, const unsigned short* __restrict__ W_npT,
    const float* __restrict__ b_np,
    float* __restrict__ out_np, float* __restrict__ out_stop)
{
    __shared__ __align__(16) float sF[4][32][FPAD];
    __shared__ int sB[128];

    const int t = threadIdx.x;
    const int wv = t >> 6, lane = t & 63;
    const int mr = lane & 31, half = lane >> 5;
    const int nb = blockIdx.x * 128;

    if (t < 128) {
        int n = nb + t;
        sB[t] = (n < NN) ? batch[n] : 0;
    }

    const int node = nb + wv * 32 + mr;

    f32x16 acc0, acc1;
    #pragma unroll
    for (int r = 0; r < 16; ++r) { acc0[r] = 0.f; acc1[r] = 0.f; }

    #pragma unroll
    for (int c = 0; c < 4; ++c) {
        short8v a;
        if (node < NN) {
            a = *(const short8v*)(hn16 + (size_t)node * 64 + c * 16 + half * 8);
        } else {
            #pragma unroll
            for (int q = 0; q < 8; ++q) a[q] = 0;
        }
        short8v b0 = *(const short8v*)(W1aT + (size_t)mr * 64        + c * 16 + half * 8);
        short8v b1 = *(const short8v*)(W1aT + (size_t)(mr + 32) * 64 + c * 16 + half * 8);
        acc0 = __builtin_amdgcn_mfma_f32_32x32x16_bf16(a, b0, acc0, 0, 0, 0);
        acc1 = __builtin_amdgcn_mfma_f32_32x32x16_bf16(a, b1, acc1, 0, 0, 0);
    }
    __syncthreads();

    #pragma unroll
    for (int r = 0; r < 16; ++r) {
        int row = (r & 3) + 8 * (r >> 2) + 4 * half;
        int g = sB[wv * 32 + row];
        float p0 = pg[(size_t)g * 64 + mr];
        float p1 = pg[(size_t)g * 64 + 32 + mr];
        sF[wv][row][mr]      = fmaxf(acc0[r] + p0, 0.f);
        sF[wv][row][32 + mr] = fmaxf(acc1[r] + p1, 0.f);
    }

    f32x16 acc2, acc3;
    #pragma unroll
    for (int r = 0; r < 16; ++r) { acc2[r] = 0.f; acc3[r] = 0.f; }

    #pragma unroll
    for (int c = 0; c < 4; ++c) {
        const float* fp = &sF[wv][mr][c * 16 + half * 8];
        float4 u0 = *(const float4*)(fp);
        float4 u1 = *(const float4*)(fp + 4);
        union { short8v v; unsigned u[4]; } A;
        A.u[0] = cvtpk(u0.x, u0.y); A.u[1] = cvtpk(u0.z, u0.w);
        A.u[2] = cvtpk(u1.x, u1.y); A.u[3] = cvtpk(u1.z, u1.w);
        short8v a = A.v;
        short8v b0 = *(const short8v*)(W_npT + (size_t)mr * 64        + c * 16 + half * 8);
        short8v b1 = *(const short8v*)(W_npT + (size_t)(mr + 32) * 64 + c * 16 + half * 8);
        acc2 = __builtin_amdgcn_mfma_f32_32x32x16_bf16(a, b0, acc2, 0, 0, 0);
        acc3 = __builtin_amdgcn_mfma_f32_32x32x16_bf16(a, b1, acc3, 0, 0, 0);
    }

    float bn1 = b_np[mr];
    float bn2 = (mr < 8) ? b_np[32 + mr] : 0.f;

    #pragma unroll
    for (int r = 0; r < 16; ++r) {
        int row = (r & 3) + 8 * (r >> 2) + 4 * half;
        int n = nb + wv * 32 + row;
        float v1 = acc2[r] + bn1;
        float v2 = acc3[r] + bn2;
        float m = (mr < 8) ? fmaxf(v1, v2) : v1;
        #pragma unroll
        for (int off = 16; off; off >>= 1) m = fmaxf(m, __shfl_xor(m, off));
        float s = expf(v1 - m) + ((mr < 8) ? expf(v2 - m) : 0.f);
        #pragma unroll
        for (int off = 16; off; off >>= 1) s += __shfl_xor(s, off);
        float ls = m + logf(s);
        if (n < NN) {
            out_np[(size_t)n * CC + mr] = v1 - ls;
            if (mr < 8) out_np[(size_t)n * CC + 32 + mr] = v2 - ls;
            if (mr == 0) out_stop[n] = sg[sB[wv * 32 + row]];
        }
    }
}

extern "C" void kernel_launch(void* const* d_in, const int* in_sizes, int n_in,
                              void* d_out, int out_size, void* d_ws, size_t ws_size,
                              hipStream_t stream)
{
    (void)in_sizes; (void)n_in; (void)out_size;
    const float* x        = (const float*)d_in[0];
    const int*   ei       = (const int*)d_in[1];
    const float* ea       = (const float*)d_in[2];
    const int*   batch    = (const int*)d_in[3];
    const float* pocket   = (const float*)d_in[4];
    const float* W_e1     = (const float*)d_in[5];
    const float* b_e1     = (const float*)d_in[6];
    const float* W_e2     = (const float*)d_in[7];
    const float* b_e2     = (const float*)d_in[8];
    const float* root     = (const float*)d_in[9];
    const float* conv_b   = (const float*)d_in[10];
    const float* Wg       = (const float*)d_in[11];
    const float* bg       = (const float*)d_in[12];
    const float* W_fc1    = (const float*)d_in[13];
    const float* b_fc1    = (const float*)d_in[14];
    const float* W_np     = (const float*)d_in[15];
    const float* b_np     = (const float*)d_in[16];
    const float* W_sp     = (const float*)d_in[17];
    const float* b_sp     = (const float*)d_in[18];

    char* wsb = (char*)d_ws;
    float* agg    = (float*)wsb;                         // NN*64 (atomic fallback only)
    int*   base   = (int*)(agg + (size_t)NN * 64);       // NN+4
    int*   bsum   = base + NN + 4;                       // 256
    int*   cursor = bsum + 256;                          // NN
    int*   rank   = cursor + NN;                         // EE
    float* gate   = (float*)(rank + EE);                 // NN
    float* pg     = gate + NN;                           // GG*64
    float* sg     = pg + (size_t)GG * 64;                // GG
    unsigned short* hn16  = (unsigned short*)(sg + GG);  // NN*64 u16
    unsigned short* W2c   = hn16 + (size_t)NN * 64;      // W2SZ
    unsigned short* W1aT  = W2c + W2SZ;                  // 4096
    unsigned short* W_npT = W1aT + 4096;                 // 4096
    unsigned short* W1e   = W_npT + 4096;                // 512
    size_t head = (size_t)((char*)(W1e + 512) - wsb);
    size_t msg_off = (head + 255) & ~(size_t)255;
    unsigned short* msgb = (unsigned short*)(wsb + msg_off);   // EE*64 u16
    size_t need = msg_off + (size_t)EE * 64 * sizeof(unsigned short);
    const bool twophase = (ws_size >= need);

    k0_prep<<<(W2SZ + 8704 + NN + 255) / 256, 256, 0, stream>>>(
        W_e2, b_e2, W_fc1, W_np, W_e1, W2c, W1aT, W_npT, W1e, cursor);

    kE_local<<<(EE + 255) / 256, 256, 0, stream>>>(ei, cursor, rank);
    kB_scan1<<<NBLK, 256, 0, stream>>>(cursor, base, bsum);
    kC_scan2<<<1, 256, 0, stream>>>(bsum);

    if (twophase) {
        k1_mfma<true><<<(EE + 127) / 128, 256, 0, stream>>>(
            x, ei, ea, W1e, b_e1, W2c, rank, base, bsum, msgb, agg);
        k2_red<<<NN / 4, 256, 0, stream>>>(msgb, base, bsum, x, root, conv_b,
                                           hn16, Wg, bg, gate);
    } else {
        hipMemsetAsync(agg, 0, (size_t)NN * 64 * sizeof(float), stream);
        k1_mfma<false><<<(EE + 127) / 128, 256, 0, stream>>>(
            x, ei, ea, W1e, b_e1, W2c, rank, base, bsum, msgb, agg);
        k2_node<<<NN / 4, 256, 0, stream>>>(agg, base, bsum, x, root, conv_b,
                                            hn16, Wg, bg, gate);
    }

    k3_pool<<<GG, 64, 0, stream>>>(gate, batch, hn16, pocket, W_fc1, b_fc1, W_sp, b_sp, pg, sg);

    float* out_np   = (float*)d_out;
    float* out_stop = out_np + (size_t)NN * CC;
    k4_mfma<<<(NN + 127) / 128, 256, 0, stream>>>(hn16, batch, pg, sg, W1aT, W_npT, b_np,
                                                  out_np, out_stop);
}

// Round 15
// 262.013 us; speedup vs baseline: 1.0033x; 1.0033x over previous
//
#include <hip/hip_runtime.h>
#include <hip/hip_bf16.h>
#include <math.h>

#define NN 150000
#define EE 600000
#define GG 5000
#define NI 16
#define EI 8
#define GFD 32
#define HH 64
#define CC 40

#define W2SZ (68 * 1024)   // 68 chunks (64 real + bias@64 + 3 zero) x 64 rows x 16 k, chunk-major
#define EHS 72             // u16 stride of sEHT2 rows (144B, 16B-aligned)
#define FPAD 68
#define NBLK ((NN + 1023) / 1024)

typedef __attribute__((ext_vector_type(8))) short short8v;
typedef __attribute__((ext_vector_type(8))) unsigned short ushort8v;
typedef __attribute__((ext_vector_type(16))) float f32x16;
typedef __attribute__((ext_vector_type(2))) float f32x2;

__device__ __forceinline__ unsigned short f2bf(float f) {
    __hip_bfloat16 h = __float2bfloat16(f);
    return __builtin_bit_cast(unsigned short, h);
}
__device__ __forceinline__ float bf2f(unsigned short u) {
    return __uint_as_float(((unsigned)u) << 16);
}
__device__ __forceinline__ unsigned cvtpk(float lo, float hi) {
    unsigned r;
    asm("v_cvt_pk_bf16_f32 %0, %1, %2" : "=v"(r) : "v"(lo), "v"(hi));
    return r;
}
__device__ __forceinline__ f32x2 pkmul(f32x2 a, f32x2 b) {
    f32x2 p;
    asm("v_pk_mul_f32 %0, %1, %2" : "=v"(p) : "v"(a), "v"(b));
    return p;
}
__device__ __forceinline__ short8v zfrag(float eh, const f32x2 (&xs2)[4]) {
    f32x2 ehp; ehp[0] = eh; ehp[1] = eh;
    union { short8v v; unsigned u[4]; } A;
    #pragma unroll
    for (int q = 0; q < 4; ++q) {
        f32x2 p = pkmul(ehp, xs2[q]);
        A.u[q] = cvtpk(p[0], p[1]);
    }
    return A.v;
}
__device__ __forceinline__ short8v xfrag(const f32x2 (&xs2)[4]) {
    union { short8v v; unsigned u[4]; } A;
    #pragma unroll
    for (int q = 0; q < 4; ++q)
        A.u[q] = cvtpk(xs2[q][0], xs2[q][1]);
    return A.v;
}

// ---------------- K0: prep bf16 weight views + zero cursor + zero gcur ----------------
__global__ void k0_prep(const float* __restrict__ W_e2, const float* __restrict__ b_e2,
                        const float* __restrict__ W_fc1, const float* __restrict__ W_np,
                        const float* __restrict__ W_e1,
                        unsigned short* __restrict__ W2c,
                        unsigned short* __restrict__ W1aT,
                        unsigned short* __restrict__ W_npT,
                        unsigned short* __restrict__ W1e,
                        int* __restrict__ cursor, int* __restrict__ gcur)
{
    int idx = blockIdx.x * 256 + threadIdx.x;
    if (idx < W2SZ) {
        int c = idx >> 10, rem = idx & 1023;
        int r = rem >> 4, kk = rem & 15;
        float v = 0.f;
        if (c < 64)       v = W_e2[c * 1024 + kk * 64 + r];
        else if (c == 64) v = b_e2[kk * 64 + r];
        W2c[idx] = f2bf(v);
    } else if (idx < W2SZ + 4096) {
        int i = idx - W2SZ;
        int h = i >> 6, k = i & 63;
        W1aT[i] = f2bf(W_fc1[k * 64 + h]);
    } else if (idx < W2SZ + 8192) {
        int i = idx - W2SZ - 4096;
        int c = i >> 6, h = i & 63;
        W_npT[i] = f2bf(c < CC ? W_np[h * CC + c] : 0.f);
    } else if (idx < W2SZ + 8704) {
        int i = idx - W2SZ - 8192;   // W1e[col][q] = W_e1[q][col]
        int col = i >> 3, q = i & 7;
        W1e[i] = f2bf(W_e1[q * 64 + col]);
    } else if (idx < W2SZ + 8704 + NN) {
        cursor[idx - W2SZ - 8704] = 0;
    } else if (idx == W2SZ + 8704 + NN) {
        gcur[0] = 0;
    }
}

// ---------------- kE_local: local rank within dst + counts ----------------
__global__ void kE_local(const int* __restrict__ ei, int* __restrict__ cursor,
                         int* __restrict__ rank)
{
    int e = blockIdx.x * 256 + threadIdx.x;
    if (e < EE) rank[e] = atomicAdd(&cursor[ei[EE + e]], 1);
}

// ---------------- kB_scan: per-block exclusive scan + atomic global offset ----------------
// Block-order of offsets is arbitrary; per-node slot contiguity (all k1/k2 need) holds.
__global__ void kB_scan(const int* __restrict__ cnt, int* __restrict__ base,
                        int* __restrict__ gcur)
{
    __shared__ int sS[256];
    __shared__ int sOff;
    int b = blockIdx.x, t = threadIdx.x;
    int i0 = b * 1024 + t * 4;
    int v0 = (i0 + 0 < NN) ? cnt[i0 + 0] : 0;
    int v1 = (i0 + 1 < NN) ? cnt[i0 + 1] : 0;
    int v2 = (i0 + 2 < NN) ? cnt[i0 + 2] : 0;
    int v3 = (i0 + 3 < NN) ? cnt[i0 + 3] : 0;
    int tot = v0 + v1 + v2 + v3;
    sS[t] = tot;
    __syncthreads();
    int acc = tot;
    for (int off = 1; off < 256; off <<= 1) {
        int xv = (t >= off) ? sS[t - off] : 0;
        __syncthreads();
        acc += xv;
        sS[t] = acc;
        __syncthreads();
    }
    if (t == 255) sOff = atomicAdd(gcur, acc);
    __syncthreads();
    int run = acc - tot + sOff;
    if (i0 + 0 < NN) base[i0 + 0] = run; run += v0;
    if (i0 + 1 < NN) base[i0 + 1] = run; run += v1;
    if (i0 + 2 < NN) base[i0 + 2] = run; run += v2;
    if (i0 + 3 < NN) base[i0 + 3] = run;
}

// ---------------- K1: M=64 x N=64 wave tiles + transposed-eh LDS ----------------
template<bool TWOPHASE>
__global__ __launch_bounds__(256, 4) void k1_mfma(
    const float* __restrict__ x, const int* __restrict__ ei,
    const float* __restrict__ ea,
    const unsigned short* __restrict__ W1e, const float* __restrict__ b_e1,
    const unsigned short* __restrict__ W2c,
    const int* __restrict__ rank, const int* __restrict__ base,
    unsigned* __restrict__ msg16, float* __restrict__ agg)
{
    __shared__ unsigned short sEHT2[256][EHS];   // [edge][k] bf16, transposed
    __shared__ int sIdx[256];

    const int t = threadIdx.x;
    const long long eb = (long long)blockIdx.x * 256;

    const int lane = t & 63;
    const int w = t >> 6;
    const int mr = lane & 31;
    const int half = lane >> 5;
    const int mb = w * 64;

    {
        long long ge = eb + t;
        if (ge < EE) {
            int d = ei[EE + ge];
            sIdx[t] = TWOPHASE ? (base[d] + rank[ge]) : d;
        } else {
            sIdx[t] = -1;
        }
    }

    // ---- edge MLP layer 1 via MFMA (wave's own 64 edges: 2 M-subtiles x 2 k-col tiles) ----
    {
        short8v bW0, bW1;
        if (half == 0) {
            bW0 = *(const short8v*)(W1e + (size_t)mr * 8);
            bW1 = *(const short8v*)(W1e + (size_t)(32 + mr) * 8);
        } else {
            #pragma unroll
            for (int q = 0; q < 8; ++q) { bW0[q] = 0; bW1[q] = 0; }
        }
        float bias0 = b_e1[mr];
        float bias1 = b_e1[32 + mr];
        #pragma unroll
        for (int m = 0; m < 2; ++m) {
            long long ge = eb + mb + m * 32 + mr;
            short8v a;
            if (half == 0 && ge < EE) {
                const float4* eap = (const float4*)(ea + ge * EI);
                float4 u0 = eap[0], u1 = eap[1];
                union { short8v v; unsigned u[4]; } A;
                A.u[0] = cvtpk(u0.x, u0.y); A.u[1] = cvtpk(u0.z, u0.w);
                A.u[2] = cvtpk(u1.x, u1.y); A.u[3] = cvtpk(u1.z, u1.w);
                a = A.v;
            } else {
                #pragma unroll
                for (int q = 0; q < 8; ++q) a[q] = 0;
            }
            #pragma unroll
            for (int n = 0; n < 2; ++n) {
                f32x16 c_;
                #pragma unroll
                for (int r = 0; r < 16; ++r) c_[r] = 0.f;
                c_ = __builtin_amdgcn_mfma_f32_32x32x16_bf16(a, n ? bW1 : bW0, c_, 0, 0, 0);
                int kcol = n * 32 + mr;
                float bias = n ? bias1 : bias0;
                #pragma unroll
                for (int r = 0; r < 16; ++r) {
                    int row = (r & 3) + 8 * (r >> 2) + 4 * half;
                    sEHT2[mb + m * 32 + row][kcol] = f2bf(fmaxf(c_[r] + bias, 0.f));
                }
            }
        }
    }

    // ---- per-lane xs gather (2 edges) ----
    f32x2 xs0[4], xs1[4];
    {
        long long g0 = eb + mb + mr;
        long long g1 = g0 + 32;
        if (g0 < EE) {
            int s0 = ei[g0];
            const float4* xp = (const float4*)(x + (size_t)s0 * NI + half * 8);
            float4 u0 = xp[0], u1 = xp[1];
            xs0[0][0]=u0.x; xs0[0][1]=u0.y; xs0[1][0]=u0.z; xs0[1][1]=u0.w;
            xs0[2][0]=u1.x; xs0[2][1]=u1.y; xs0[3][0]=u1.z; xs0[3][1]=u1.w;
        } else {
            #pragma unroll
            for (int q = 0; q < 4; ++q) { xs0[q][0] = 0.f; xs0[q][1] = 0.f; }
        }
        if (g1 < EE) {
            int s1 = ei[g1];
            const float4* xp = (const float4*)(x + (size_t)s1 * NI + half * 8);
            float4 u0 = xp[0], u1 = xp[1];
            xs1[0][0]=u0.x; xs1[0][1]=u0.y; xs1[1][0]=u0.z; xs1[1][1]=u0.w;
            xs1[2][0]=u1.x; xs1[2][1]=u1.y; xs1[3][0]=u1.z; xs1[3][1]=u1.w;
        } else {
            #pragma unroll
            for (int q = 0; q < 4; ++q) { xs1[q][0] = 0.f; xs1[q][1] = 0.f; }
        }
    }
    __syncthreads();

    f32x16 acc00, acc01, acc10, acc11;
    #pragma unroll
    for (int r = 0; r < 16; ++r) { acc00[r] = 0.f; acc01[r] = 0.f; acc10[r] = 0.f; acc11[r] = 0.f; }

    // chunk-major B: wave's two loads per step cover the chunk's contiguous 2KB
    const unsigned short* Bq0 = W2c + mr * 16 + half * 8;   // cols 0..31
    const unsigned short* Bq1 = Bq0 + 512;                  // cols 32..63

    short8v bA0 = *(const short8v*)(Bq0);
    short8v bA1 = *(const short8v*)(Bq1);
    short8v bB0 = *(const short8v*)(Bq0 + 1024);
    short8v bB1 = *(const short8v*)(Bq1 + 1024);

    const unsigned short* ehp0 = &sEHT2[mb + mr][0];
    const unsigned short* ehp1 = ehp0 + 32 * EHS;

    ushort8v eh0 = *(const ushort8v*)(ehp0);
    ushort8v eh1 = *(const ushort8v*)(ehp1);

    #pragma unroll 1
    for (int cb = 0; cb < 64; cb += 8) {
        ushort8v nx0 = *(const ushort8v*)(ehp0 + cb + 8);   // cb=56 reads pad cols (unused)
        ushort8v nx1 = *(const ushort8v*)(ehp1 + cb + 8);
        #pragma unroll
        for (int j = 0; j < 8; j += 2) {
            int c = cb + j;
            {
                short8v p0 = *(const short8v*)(Bq0 + (c + 2) * 1024);
                short8v p1 = *(const short8v*)(Bq1 + (c + 2) * 1024);
                short8v a0 = zfrag(bf2f(eh0[j]), xs0);
                short8v a1 = zfrag(bf2f(eh1[j]), xs1);
                __builtin_amdgcn_s_setprio(1);
                acc00 = __builtin_amdgcn_mfma_f32_32x32x16_bf16(a0, bA0, acc00, 0, 0, 0);
                acc01 = __builtin_amdgcn_mfma_f32_32x32x16_bf16(a0, bA1, acc01, 0, 0, 0);
                acc10 = __builtin_amdgcn_mfma_f32_32x32x16_bf16(a1, bA0, acc10, 0, 0, 0);
                acc11 = __builtin_amdgcn_mfma_f32_32x32x16_bf16(a1, bA1, acc11, 0, 0, 0);
                __builtin_amdgcn_s_setprio(0);
                bA0 = p0; bA1 = p1;
            }
            {
                short8v p0 = *(const short8v*)(Bq0 + (c + 3) * 1024);
                short8v p1 = *(const short8v*)(Bq1 + (c + 3) * 1024);
                short8v a0 = zfrag(bf2f(eh0[j + 1]), xs0);
                short8v a1 = zfrag(bf2f(eh1[j + 1]), xs1);
                __builtin_amdgcn_s_setprio(1);
                acc00 = __builtin_amdgcn_mfma_f32_32x32x16_bf16(a0, bB0, acc00, 0, 0, 0);
                acc01 = __builtin_amdgcn_mfma_f32_32x32x16_bf16(a0, bB1, acc01, 0, 0, 0);
                acc10 = __builtin_amdgcn_mfma_f32_32x32x16_bf16(a1, bB0, acc10, 0, 0, 0);
                acc11 = __builtin_amdgcn_mfma_f32_32x32x16_bf16(a1, bB1, acc11, 0, 0, 0);
                __builtin_amdgcn_s_setprio(0);
                bB0 = p0; bB1 = p1;
            }
        }
        eh0 = nx0; eh1 = nx1;
    }
    // bias chunk c=64: eh = 1 -> A = bf16(xs); B in bA (prefetched at c=62)
    {
        short8v a0 = xfrag(xs0);
        short8v a1 = xfrag(xs1);
        __builtin_amdgcn_s_setprio(1);
        acc00 = __builtin_amdgcn_mfma_f32_32x32x16_bf16(a0, bA0, acc00, 0, 0, 0);
        acc01 = __builtin_amdgcn_mfma_f32_32x32x16_bf16(a0, bA1, acc01, 0, 0, 0);
        acc10 = __builtin_amdgcn_mfma_f32_32x32x16_bf16(a1, bA0, acc10, 0, 0, 0);
        acc11 = __builtin_amdgcn_mfma_f32_32x32x16_bf16(a1, bA1, acc11, 0, 0, 0);
        __builtin_amdgcn_s_setprio(0);
    }

    // ---- epilogue: paired-u32 bf16 stores ----
    #pragma unroll
    for (int r = 0; r < 16; ++r) {
        int row = (r & 3) + 8 * (r >> 2) + 4 * half;
        int i0 = sIdx[mb + row];
        int i1 = sIdx[mb + 32 + row];
        if (TWOPHASE) {
            if (i0 >= 0) msg16[(size_t)i0 * 32 + mr] = cvtpk(acc00[r], acc01[r]);
            if (i1 >= 0) msg16[(size_t)i1 * 32 + mr] = cvtpk(acc10[r], acc11[r]);
        } else {
            if (i0 >= 0) {
                atomicAdd(&agg[(size_t)i0 * 64 + mr],      acc00[r]);
                atomicAdd(&agg[(size_t)i0 * 64 + 32 + mr], acc01[r]);
            }
            if (i1 >= 0) {
                atomicAdd(&agg[(size_t)i1 * 64 + mr],      acc10[r]);
                atomicAdd(&agg[(size_t)i1 * 64 + 32 + mr], acc11[r]);
            }
        }
    }
}

// ---------------- K2 (two-phase): stream-reduce paired msg16 + mean + root + relu + gate ----------------
__global__ __launch_bounds__(256) void k2_red(
    const unsigned* __restrict__ msg16, const int* __restrict__ base,
    const int* __restrict__ deg,
    const float* __restrict__ x, const float* __restrict__ root,
    const float* __restrict__ conv_bias,
    unsigned short* __restrict__ hn16,
    const float* __restrict__ Wg, const float* __restrict__ bg,
    float* __restrict__ gate)
{
    __shared__ float sroot[16][64];
    int t = threadIdx.x;
    #pragma unroll
    for (int q = 0; q < 4; ++q) {
        int i = q * 256 + t;
        sroot[i >> 6][i & 63] = root[i];
    }
    __syncthreads();

    int n = blockIdx.x * 4 + (t >> 6);
    int l = t & 63;
    int mr = l & 31, so = l >> 5;
    int s = base[n];
    int e = s + deg[n];

    float alo = 0.f, ahi = 0.f;
    int sl = s + so;
    for (; sl + 2 < e; sl += 4) {
        unsigned u0 = msg16[(size_t)sl * 32 + mr];
        unsigned u1 = msg16[(size_t)(sl + 2) * 32 + mr];
        alo += __uint_as_float(u0 << 16) + __uint_as_float(u1 << 16);
        ahi += __uint_as_float(u0 & 0xFFFF0000u) + __uint_as_float(u1 & 0xFFFF0000u);
    }
    if (sl < e) {
        unsigned u = msg16[(size_t)sl * 32 + mr];
        alo += __uint_as_float(u << 16);
        ahi += __uint_as_float(u & 0xFFFF0000u);
    }
    alo += __shfl_xor(alo, 32);
    ahi += __shfl_xor(ahi, 32);
    float acc = (l < 32) ? alo : ahi;

    float inv = 1.0f / fmaxf((float)(e - s), 1.0f);
    float v = acc * inv + conv_bias[l];
    float xv = (l < 16) ? x[(size_t)n * NI + l] : 0.f;
    #pragma unroll
    for (int i = 0; i < 16; ++i)
        v = fmaf(__shfl(xv, i), sroot[i][l], v);
    v = fmaxf(v, 0.f);
    hn16[(size_t)n * 64 + l] = f2bf(v);

    float gv = v * Wg[l];
    #pragma unroll
    for (int off = 32; off; off >>= 1) gv += __shfl_xor(gv, off);
    if (l == 0) gate[n] = gv + bg[0];
}

// ---------------- K2 (fallback): mean + root + relu over agg ----------------
__global__ __launch_bounds__(256) void k2_node(
    const float* __restrict__ agg, const int* __restrict__ deg,
    const float* __restrict__ x, const float* __restrict__ root,
    const float* __restrict__ conv_bias,
    unsigned short* __restrict__ hn16,
    const float* __restrict__ Wg, const float* __restrict__ bg,
    float* __restrict__ gate)
{
    int t = threadIdx.x;
    int n = blockIdx.x * 4 + (t >> 6);
    int h = t & 63;
    float inv = 1.0f / fmaxf((float)deg[n], 1.0f);
    float v = agg[(size_t)n * 64 + h] * inv + conv_bias[h];
    const float* xp = x + (size_t)n * NI;
    #pragma unroll
    for (int i = 0; i < NI; ++i) v += xp[i] * root[i * 64 + h];
    v = fmaxf(v, 0.f);
    hn16[(size_t)n * 64 + h] = f2bf(v);
    float gv = v * Wg[h];
    #pragma unroll
    for (int off = 32; off; off >>= 1) gv += __shfl_xor(gv, off);
    if (h == 0) gate[n] = gv + bg[0];
}

// ---------------- K3: per-graph pooling + pg/sg precompute ----------------
__device__ __forceinline__ int lbound(const int* __restrict__ b, int v) {
    int lo = 0, hi = NN;
    while (lo < hi) { int mid = (lo + hi) >> 1; if (b[mid] < v) lo = mid + 1; else hi = mid; }
    return lo;
}

__global__ __launch_bounds__(64) void k3_pool(
    const float* __restrict__ gate, const int* __restrict__ batch,
    const unsigned short* __restrict__ hn16, const float* __restrict__ pocket,
    const float* __restrict__ W_fc1, const float* __restrict__ b_fc1,
    const float* __restrict__ W_sp, const float* __restrict__ b_sp,
    float* __restrict__ pg, float* __restrict__ sg)
{
    int g = blockIdx.x;
    int lane = threadIdx.x;
    int s = lbound(batch, g);
    int e = lbound(batch, g + 1);

    float gcv = 0.f;
    if (e > s) {
        float m = -INFINITY;
        for (int n = s + lane; n < e; n += 64) m = fmaxf(m, gate[n]);
        #pragma unroll
        for (int off = 32; off; off >>= 1) m = fmaxf(m, __shfl_xor(m, off));
        float acc = 0.f, den = 0.f;
        int n = s;
        for (; n + 2 <= e; n += 2) {
            float e0 = expf(gate[n] - m);
            float e1 = expf(gate[n + 1] - m);
            float h0 = bf2f(hn16[(size_t)n * 64 + lane]);
            float h1 = bf2f(hn16[(size_t)(n + 1) * 64 + lane]);
            den += e0 + e1;
            acc = fmaf(e0, h0, acc);
            acc = fmaf(e1, h1, acc);
        }
        if (n < e) {
            float ev = expf(gate[n] - m);
            den += ev;
            acc = fmaf(ev, bf2f(hn16[(size_t)n * 64 + lane]), acc);
        }
        gcv = acc / den;
    }

    float sv = gcv * W_sp[lane];
    #pragma unroll
    for (int off = 32; off; off >>= 1) sv += __shfl_xor(sv, off);
    if (lane == 0) sg[g] = 1.f / (1.f + expf(-(sv + b_sp[0])));

    float pk = (lane < GFD) ? pocket[(size_t)g * GFD + lane] : 0.f;
    float pgv = b_fc1[lane];
    #pragma unroll 8
    for (int kk = 0; kk < 64; ++kk)
        pgv = fmaf(__shfl(gcv, kk), W_fc1[(64 + kk) * 64 + lane], pgv);
    #pragma unroll 8
    for (int kk = 0; kk < 32; ++kk)
        pgv = fmaf(__shfl(pk, kk), W_fc1[(128 + kk) * 64 + lane], pgv);
    pg[(size_t)g * 64 + lane] = pgv;
}

// ---------------- K4: MFMA head ----------------
__global__ __launch_bounds__(256, 4) void k4_mfma(
    const unsigned short* __restrict__ hn16, const int* __restrict__ batch,
    const float* __restrict__ pg, const float* __restrict__ sg,
    const unsigned short* __restrict__ W1aT, const unsigned short* __restrict__ W_npT,
    const float* __restrict__ b_np,
    float* __restrict__ out_np, float* __restrict__ out_stop)
{
    __shared__ __align__(16) float sF[4][32][FPAD];
    __shared__ int sB[128];

    const int t = threadIdx.x;
    const int wv = t >> 6, lane = t & 63;
    const int mr = lane & 31, half = lane >> 5;
    const int nb = blockIdx.x * 128;

    if (t < 128) {
        int n = nb + t;
        sB[t] = (n < NN) ? batch[n] : 0;
    }

    const int node = nb + wv * 32 + mr;

    f32x16 acc0, acc1;
    #pragma unroll
    for (int r = 0; r < 16; ++r) { acc0[r] = 0.f; acc1[r] = 0.f; }

    #pragma unroll
    for (int c = 0; c < 4; ++c) {
        short8v a;
        if (node < NN) {
            a = *(const short8v*)(hn16 + (size_t)node * 64 + c * 16 + half * 8);
        } else {
            #pragma unroll
            for (int q = 0; q < 8; ++q) a[q] = 0;
        }
        short8v b0 = *(const short8v*)(W1aT + (size_t)mr * 64        + c * 16 + half * 8);
        short8v b1 = *(const short8v*)(W1aT + (size_t)(mr + 32) * 64 + c * 16 + half * 8);
        acc0 = __builtin_amdgcn_mfma_f32_32x32x16_bf16(a, b0, acc0, 0, 0, 0);
        acc1 = __builtin_amdgcn_mfma_f32_32x32x16_bf16(a, b1, acc1, 0, 0, 0);
    }
    __syncthreads();

    #pragma unroll
    for (int r = 0; r < 16; ++r) {
        int row = (r & 3) + 8 * (r >> 2) + 4 * half;
        int g = sB[wv * 32 + row];
        float p0 = pg[(size_t)g * 64 + mr];
        float p1 = pg[(size_t)g * 64 + 32 + mr];
        sF[wv][row][mr]      = fmaxf(acc0[r] + p0, 0.f);
        sF[wv][row][32 + mr] = fmaxf(acc1[r] + p1, 0.f);
    }

    f32x16 acc2, acc3;
    #pragma unroll
    for (int r = 0; r < 16; ++r) { acc2[r] = 0.f; acc3[r] = 0.f; }

    #pragma unroll
    for (int c = 0; c < 4; ++c) {
        const float* fp = &sF[wv][mr][c * 16 + half * 8];
        float4 u0 = *(const float4*)(fp);
        float4 u1 = *(const float4*)(fp + 4);
        union { short8v v; unsigned u[4]; } A;
        A.u[0] = cvtpk(u0.x, u0.y); A.u[1] = cvtpk(u0.z, u0.w);
        A.u[2] = cvtpk(u1.x, u1.y); A.u[3] = cvtpk(u1.z, u1.w);
        short8v a = A.v;
        short8v b0 = *(const short8v*)(W_npT + (size_t)mr * 64        + c * 16 + half * 8);
        short8v b1 = *(const short8v*)(W_npT + (size_t)(mr + 32) * 64 + c * 16 + half * 8);
        acc2 = __builtin_amdgcn_mfma_f32_32x32x16_bf16(a, b0, acc2, 0, 0, 0);
        acc3 = __builtin_amdgcn_mfma_f32_32x32x16_bf16(a, b1, acc3, 0, 0, 0);
    }

    float bn1 = b_np[mr];
    float bn2 = (mr < 8) ? b_np[32 + mr] : 0.f;

    #pragma unroll
    for (int r = 0; r < 16; ++r) {
        int row = (r & 3) + 8 * (r >> 2) + 4 * half;
        int n = nb + wv * 32 + row;
        float v1 = acc2[r] + bn1;
        float v2 = acc3[r] + bn2;
        float m = (mr < 8) ? fmaxf(v1, v2) : v1;
        #pragma unroll
        for (int off = 16; off; off >>= 1) m = fmaxf(m, __shfl_xor(m, off));
        float s = expf(v1 - m) + ((mr < 8) ? expf(v2 - m) : 0.f);
        #pragma unroll
        for (int off = 16; off; off >>= 1) s += __shfl_xor(s, off);
        float ls = m + logf(s);
        if (n < NN) {
            out_np[(size_t)n * CC + mr] = v1 - ls;
            if (mr < 8) out_np[(size_t)n * CC + 32 + mr] = v2 - ls;
            if (mr == 0) out_stop[n] = sg[sB[wv * 32 + row]];
        }
    }
}

extern "C" void kernel_launch(void* const* d_in, const int* in_sizes, int n_in,
                              void* d_out, int out_size, void* d_ws, size_t ws_size,
                              hipStream_t stream)
{
    (void)in_sizes; (void)n_in; (void)out_size;
    const float* x        = (const float*)d_in[0];
    const int*   ei       = (const int*)d_in[1];
    const float* ea       = (const float*)d_in[2];
    const int*   batch    = (const int*)d_in[3];
    const float* pocket   = (const float*)d_in[4];
    const float* W_e1     = (const float*)d_in[5];
    const float* b_e1     = (const float*)d_in[6];
    const float* W_e2     = (const float*)d_in[7];
    const float* b_e2     = (const float*)d_in[8];
    const float* root     = (const float*)d_in[9];
    const float* conv_b   = (const float*)d_in[10];
    const float* Wg       = (const float*)d_in[11];
    const float* bg       = (const float*)d_in[12];
    const float* W_fc1    = (const float*)d_in[13];
    const float* b_fc1    = (const float*)d_in[14];
    const float* W_np     = (const float*)d_in[15];
    const float* b_np     = (const float*)d_in[16];
    const float* W_sp     = (const float*)d_in[17];
    const float* b_sp     = (const float*)d_in[18];

    char* wsb = (char*)d_ws;
    float* agg    = (float*)wsb;                         // NN*64 (atomic fallback only)
    int*   base   = (int*)(agg + (size_t)NN * 64);       // NN
    int*   gcur   = base + NN;                           // 1 (+pad)
    int*   cursor = gcur + 4;                            // NN (degree counts after kE)
    int*   rank   = cursor + NN;                         // EE
    float* gate   = (float*)(rank + EE);                 // NN
    float* pg     = gate + NN;                           // GG*64
    float* sg     = pg + (size_t)GG * 64;                // GG
    unsigned short* hn16  = (unsigned short*)(sg + GG);  // NN*64 u16
    unsigned short* W2c   = hn16 + (size_t)NN * 64;      // W2SZ
    unsigned short* W1aT  = W2c + W2SZ;                  // 4096
    unsigned short* W_npT = W1aT + 4096;                 // 4096
    unsigned short* W1e   = W_npT + 4096;                // 512
    size_t head = (size_t)((char*)(W1e + 512) - wsb);
    size_t msg_off = (head + 255) & ~(size_t)255;
    unsigned* msg16 = (unsigned*)(wsb + msg_off);        // EE*32 u32
    size_t need = msg_off + (size_t)EE * 32 * sizeof(unsigned);
    const bool twophase = (ws_size >= need);

    k0_prep<<<(W2SZ + 8705 + NN + 255) / 256, 256, 0, stream>>>(
        W_e2, b_e2, W_fc1, W_np, W_e1, W2c, W1aT, W_npT, W1e, cursor, gcur);

    kE_local<<<(EE + 255) / 256, 256, 0, stream>>>(ei, cursor, rank);
    kB_scan<<<NBLK, 256, 0, stream>>>(cursor, base, gcur);

    if (twophase) {
        k1_mfma<true><<<(EE + 255) / 256, 256, 0, stream>>>(
            x, ei, ea, W1e, b_e1, W2c, rank, base, msg16, agg);
        k2_red<<<NN / 4, 256, 0, stream>>>(msg16, base, cursor, x, root, conv_b,
                                           hn16, Wg, bg, gate);
    } else {
        hipMemsetAsync(agg, 0, (size_t)NN * 64 * sizeof(float), stream);
        k1_mfma<false><<<(EE + 255) / 256, 256, 0, stream>>>(
            x, ei, ea, W1e, b_e1, W2c, rank, base, msg16, agg);
        k2_node<<<NN / 4, 256, 0, stream>>>(agg, cursor, x, root, conv_b,
                                            hn16, Wg, bg, gate);
    }

    k3_pool<<<GG, 64, 0, stream>>>(gate, batch, hn16, pocket, W_fc1, b_fc1, W_sp, b_sp, pg, sg);

    float* out_np   = (float*)d_out;
    float* out_stop = out_np + (size_t)NN * CC;
    k4_mfma<<<(NN + 127) / 128, 256, 0, stream>>>(hn16, batch, pg, sg, W1aT, W_npT, b_np,
                                                  out_np, out_stop);
}

// Round 16
// 248.562 us; speedup vs baseline: 1.0575x; 1.0541x over previous
//
#include <hip/hip_runtime.h>
#include <hip/hip_bf16.h>
#include <math.h>

#define NN 150000
#define EE 600000
#define GG 5000
#define NI 16
#define EI 8
#define GFD 32
#define HH 64
#define CC 40

#define W2SZ (68 * 1024)   // 68 chunks (64 real + bias@64 + 3 zero) x 64 rows x 16 k, chunk-major
#define FPAD 68
#define NBLK ((NN + 1023) / 1024)

typedef __attribute__((ext_vector_type(8))) short short8v;
typedef __attribute__((ext_vector_type(16))) float f32x16;
typedef __attribute__((ext_vector_type(2))) float f32x2;

__device__ __forceinline__ unsigned short f2bf(float f) {
    __hip_bfloat16 h = __float2bfloat16(f);
    return __builtin_bit_cast(unsigned short, h);
}
__device__ __forceinline__ float bf2f(unsigned short u) {
    return __uint_as_float(((unsigned)u) << 16);
}
__device__ __forceinline__ unsigned cvtpk(float lo, float hi) {
    unsigned r;
    asm("v_cvt_pk_bf16_f32 %0, %1, %2" : "=v"(r) : "v"(lo), "v"(hi));
    return r;
}
__device__ __forceinline__ f32x2 pkmul(f32x2 a, f32x2 b) {
    f32x2 p;
    asm("v_pk_mul_f32 %0, %1, %2" : "=v"(p) : "v"(a), "v"(b));
    return p;
}
__device__ __forceinline__ short8v zfrag(float eh, const f32x2 (&xs2)[4]) {
    f32x2 ehp; ehp[0] = eh; ehp[1] = eh;
    union { short8v v; unsigned u[4]; } A;
    #pragma unroll
    for (int q = 0; q < 4; ++q) {
        f32x2 p = pkmul(ehp, xs2[q]);
        A.u[q] = cvtpk(p[0], p[1]);
    }
    return A.v;
}
__device__ __forceinline__ short8v xfrag(const f32x2 (&xs2)[4]) {
    union { short8v v; unsigned u[4]; } A;
    #pragma unroll
    for (int q = 0; q < 4; ++q)
        A.u[q] = cvtpk(xs2[q][0], xs2[q][1]);
    return A.v;
}

// ---------------- K0: prep bf16 weight views + zero cursor + zero gcur ----------------
__global__ void k0_prep(const float* __restrict__ W_e2, const float* __restrict__ b_e2,
                        const float* __restrict__ W_fc1, const float* __restrict__ W_np,
                        const float* __restrict__ W_e1,
                        unsigned short* __restrict__ W2c,
                        unsigned short* __restrict__ W1aT,
                        unsigned short* __restrict__ W_npT,
                        unsigned short* __restrict__ W1e,
                        int* __restrict__ cursor, int* __restrict__ gcur)
{
    int idx = blockIdx.x * 256 + threadIdx.x;
    if (idx < W2SZ) {
        int c = idx >> 10, rem = idx & 1023;
        int r = rem >> 4, kk = rem & 15;
        float v = 0.f;
        if (c < 64)       v = W_e2[c * 1024 + kk * 64 + r];
        else if (c == 64) v = b_e2[kk * 64 + r];
        W2c[idx] = f2bf(v);
    } else if (idx < W2SZ + 4096) {
        int i = idx - W2SZ;
        int h = i >> 6, k = i & 63;
        W1aT[i] = f2bf(W_fc1[k * 64 + h]);
    } else if (idx < W2SZ + 8192) {
        int i = idx - W2SZ - 4096;
        int c = i >> 6, h = i & 63;
        W_npT[i] = f2bf(c < CC ? W_np[h * CC + c] : 0.f);
    } else if (idx < W2SZ + 8704) {
        int i = idx - W2SZ - 8192;   // W1e[col][q] = W_e1[q][col]
        int col = i >> 3, q = i & 7;
        W1e[i] = f2bf(W_e1[q * 64 + col]);
    } else if (idx < W2SZ + 8704 + NN) {
        cursor[idx - W2SZ - 8704] = 0;
    } else if (idx == W2SZ + 8704 + NN) {
        gcur[0] = 0;
    }
}

// ---------------- kE_local: local rank within dst + counts ----------------
__global__ void kE_local(const int* __restrict__ ei, int* __restrict__ cursor,
                         int* __restrict__ rank)
{
    int e = blockIdx.x * 256 + threadIdx.x;
    if (e < EE) rank[e] = atomicAdd(&cursor[ei[EE + e]], 1);
}

// ---------------- kB_scan: per-block exclusive scan + atomic global offset ----------------
__global__ void kB_scan(const int* __restrict__ cnt, int* __restrict__ base,
                        int* __restrict__ gcur)
{
    __shared__ int sS[256];
    __shared__ int sOff;
    int b = blockIdx.x, t = threadIdx.x;
    int i0 = b * 1024 + t * 4;
    int v0 = (i0 + 0 < NN) ? cnt[i0 + 0] : 0;
    int v1 = (i0 + 1 < NN) ? cnt[i0 + 1] : 0;
    int v2 = (i0 + 2 < NN) ? cnt[i0 + 2] : 0;
    int v3 = (i0 + 3 < NN) ? cnt[i0 + 3] : 0;
    int tot = v0 + v1 + v2 + v3;
    sS[t] = tot;
    __syncthreads();
    int acc = tot;
    for (int off = 1; off < 256; off <<= 1) {
        int xv = (t >= off) ? sS[t - off] : 0;
        __syncthreads();
        acc += xv;
        sS[t] = acc;
        __syncthreads();
    }
    if (t == 255) sOff = atomicAdd(gcur, acc);
    __syncthreads();
    int run = acc - tot + sOff;
    if (i0 + 0 < NN) base[i0 + 0] = run; run += v0;
    if (i0 + 1 < NN) base[i0 + 1] = run; run += v1;
    if (i0 + 2 < NN) base[i0 + 2] = run; run += v2;
    if (i0 + 3 < NN) base[i0 + 3] = run;
}

// ---------------- kG: graph boundary starts (batch sorted) ----------------
__global__ void kG_bounds(const int* __restrict__ batch, int* __restrict__ gs)
{
    int n = blockIdx.x * 256 + threadIdx.x;
    if (n >= NN) return;
    int b1 = batch[n];
    int b0 = (n == 0) ? -1 : batch[n - 1];
    for (int g = b0 + 1; g <= b1; ++g) gs[g] = n;
    if (n == NN - 1)
        for (int g = b1 + 1; g <= GG; ++g) gs[g] = NN;
}

// ---------------- shared MFMA inner step (R12: chunk-major B, scalar eh LDS read) ----------------
__device__ __forceinline__ void mfma_step(
    const unsigned short (&sEHT)[65][256], int c, int pf,
    const unsigned short* __restrict__ Bq0, const unsigned short* __restrict__ Bq1,
    int mb, int mr, const f32x2 (&xs0)[4], const f32x2 (&xs1)[4],
    short8v& curb0, short8v& curb1,
    f32x16& acc00, f32x16& acc01, f32x16& acc10, f32x16& acc11)
{
    short8v n0 = *(const short8v*)(Bq0 + pf * 1024);
    short8v n1 = *(const short8v*)(Bq1 + pf * 1024);
    int cc = (c & 31) << 1;
    float eh0 = bf2f(sEHT[c][(mb + mr) ^ cc]);
    float eh1 = bf2f(sEHT[c][(mb + 32 + mr) ^ cc]);
    short8v a0 = zfrag(eh0, xs0);
    short8v a1 = zfrag(eh1, xs1);
    __builtin_amdgcn_s_setprio(1);
    acc00 = __builtin_amdgcn_mfma_f32_32x32x16_bf16(a0, curb0, acc00, 0, 0, 0);
    acc01 = __builtin_amdgcn_mfma_f32_32x32x16_bf16(a0, curb1, acc01, 0, 0, 0);
    acc10 = __builtin_amdgcn_mfma_f32_32x32x16_bf16(a1, curb0, acc10, 0, 0, 0);
    acc11 = __builtin_amdgcn_mfma_f32_32x32x16_bf16(a1, curb1, acc11, 0, 0, 0);
    __builtin_amdgcn_s_setprio(0);
    curb0 = n0; curb1 = n1;
}

// ---------------- K1 (R12 structure): MFMA edge MLP + MFMA z-GEMM ----------------
template<bool TWOPHASE>
__global__ __launch_bounds__(256, 4) void k1_mfma(
    const float* __restrict__ x, const int* __restrict__ ei,
    const float* __restrict__ ea,
    const unsigned short* __restrict__ W1e, const float* __restrict__ b_e1,
    const unsigned short* __restrict__ W2c,
    const int* __restrict__ rank, const int* __restrict__ base,
    unsigned* __restrict__ msg16, float* __restrict__ agg)
{
    __shared__ unsigned short sEHT[65][256];
    __shared__ int sIdx[256];

    const int t = threadIdx.x;
    const long long eb = (long long)blockIdx.x * 256;

    const int lane = t & 63;
    const int w = t >> 6;
    const int mr = lane & 31;
    const int half = lane >> 5;
    const int mb = w * 64;

    {
        long long ge = eb + t;
        if (ge < EE) {
            int d = ei[EE + ge];
            sIdx[t] = TWOPHASE ? (base[d] + rank[ge]) : d;
        } else {
            sIdx[t] = -1;
        }
        sEHT[64][t] = (unsigned short)0x3F80;   // bias row eh = 1.0
    }

    // ---- edge MLP layer 1 via MFMA: eh = relu(ea @ W_e1 + b_e1) -> sEHT ----
    {
        short8v bW0, bW1;
        if (half == 0) {
            bW0 = *(const short8v*)(W1e + (size_t)mr * 8);
            bW1 = *(const short8v*)(W1e + (size_t)(32 + mr) * 8);
        } else {
            #pragma unroll
            for (int q = 0; q < 8; ++q) { bW0[q] = 0; bW1[q] = 0; }
        }
        float bias0 = b_e1[mr];
        float bias1 = b_e1[32 + mr];
        #pragma unroll
        for (int m = 0; m < 2; ++m) {
            long long ge = eb + mb + m * 32 + mr;
            short8v a;
            if (half == 0 && ge < EE) {
                const float4* eap = (const float4*)(ea + ge * EI);
                float4 u0 = eap[0], u1 = eap[1];
                union { short8v v; unsigned u[4]; } A;
                A.u[0] = cvtpk(u0.x, u0.y); A.u[1] = cvtpk(u0.z, u0.w);
                A.u[2] = cvtpk(u1.x, u1.y); A.u[3] = cvtpk(u1.z, u1.w);
                a = A.v;
            } else {
                #pragma unroll
                for (int q = 0; q < 8; ++q) a[q] = 0;
            }
            #pragma unroll
            for (int n = 0; n < 2; ++n) {
                f32x16 c_;
                #pragma unroll
                for (int r = 0; r < 16; ++r) c_[r] = 0.f;
                c_ = __builtin_amdgcn_mfma_f32_32x32x16_bf16(a, n ? bW1 : bW0, c_, 0, 0, 0);
                int kcol = n * 32 + mr;
                float bias = n ? bias1 : bias0;
                #pragma unroll
                for (int r = 0; r < 16; r += 2) {
                    int row = (r & 3) + 8 * (r >> 2) + 4 * half;
                    int e0 = mb + m * 32 + row;
                    float v0 = fmaxf(c_[r]     + bias, 0.f);
                    float v1 = fmaxf(c_[r + 1] + bias, 0.f);
                    *(unsigned*)&sEHT[kcol][e0 ^ (mr << 1)] = cvtpk(v0, v1);
                }
            }
        }
    }

    // ---- per-lane xs gather ----
    f32x2 xs0[4], xs1[4];
    {
        long long g0 = eb + mb + mr;
        long long g1 = g0 + 32;
        if (g0 < EE) {
            int s0 = ei[g0];
            const float4* xp = (const float4*)(x + (size_t)s0 * NI + half * 8);
            float4 u0 = xp[0], u1 = xp[1];
            xs0[0][0]=u0.x; xs0[0][1]=u0.y; xs0[1][0]=u0.z; xs0[1][1]=u0.w;
            xs0[2][0]=u1.x; xs0[2][1]=u1.y; xs0[3][0]=u1.z; xs0[3][1]=u1.w;
        } else {
            #pragma unroll
            for (int q = 0; q < 4; ++q) { xs0[q][0] = 0.f; xs0[q][1] = 0.f; }
        }
        if (g1 < EE) {
            int s1 = ei[g1];
            const float4* xp = (const float4*)(x + (size_t)s1 * NI + half * 8);
            float4 u0 = xp[0], u1 = xp[1];
            xs1[0][0]=u0.x; xs1[0][1]=u0.y; xs1[1][0]=u0.z; xs1[1][1]=u0.w;
            xs1[2][0]=u1.x; xs1[2][1]=u1.y; xs1[3][0]=u1.z; xs1[3][1]=u1.w;
        } else {
            #pragma unroll
            for (int q = 0; q < 4; ++q) { xs1[q][0] = 0.f; xs1[q][1] = 0.f; }
        }
    }
    __syncthreads();

    f32x16 acc00, acc01, acc10, acc11;
    #pragma unroll
    for (int r = 0; r < 16; ++r) { acc00[r] = 0.f; acc01[r] = 0.f; acc10[r] = 0.f; acc11[r] = 0.f; }

    const unsigned short* Bq0 = W2c + mr * 16 + half * 8;
    const unsigned short* Bq1 = Bq0 + 512;

    short8v bA0 = *(const short8v*)(Bq0);
    short8v bA1 = *(const short8v*)(Bq1);
    short8v bB0 = *(const short8v*)(Bq0 + 1024);
    short8v bB1 = *(const short8v*)(Bq1 + 1024);

    #pragma unroll 2
    for (int c = 0; c < 64; c += 2) {
        mfma_step(sEHT, c,     c + 2, Bq0, Bq1, mb, mr, xs0, xs1, bA0, bA1, acc00, acc01, acc10, acc11);
        mfma_step(sEHT, c + 1, c + 3, Bq0, Bq1, mb, mr, xs0, xs1, bB0, bB1, acc00, acc01, acc10, acc11);
    }
    // bias chunk c=64: eh = 1 -> A = bf16(xs); B in bA (prefetched at c=62)
    {
        short8v a0 = xfrag(xs0);
        short8v a1 = xfrag(xs1);
        __builtin_amdgcn_s_setprio(1);
        acc00 = __builtin_amdgcn_mfma_f32_32x32x16_bf16(a0, bA0, acc00, 0, 0, 0);
        acc01 = __builtin_amdgcn_mfma_f32_32x32x16_bf16(a0, bA1, acc01, 0, 0, 0);
        acc10 = __builtin_amdgcn_mfma_f32_32x32x16_bf16(a1, bA0, acc10, 0, 0, 0);
        acc11 = __builtin_amdgcn_mfma_f32_32x32x16_bf16(a1, bA1, acc11, 0, 0, 0);
        __builtin_amdgcn_s_setprio(0);
    }

    #pragma unroll
    for (int r = 0; r < 16; ++r) {
        int row = (r & 3) + 8 * (r >> 2) + 4 * half;
        int i0 = sIdx[mb + row];
        int i1 = sIdx[mb + 32 + row];
        if (TWOPHASE) {
            if (i0 >= 0) msg16[(size_t)i0 * 32 + mr] = cvtpk(acc00[r], acc01[r]);
            if (i1 >= 0) msg16[(size_t)i1 * 32 + mr] = cvtpk(acc10[r], acc11[r]);
        } else {
            if (i0 >= 0) {
                atomicAdd(&agg[(size_t)i0 * 64 + mr],      acc00[r]);
                atomicAdd(&agg[(size_t)i0 * 64 + 32 + mr], acc01[r]);
            }
            if (i1 >= 0) {
                atomicAdd(&agg[(size_t)i1 * 64 + mr],      acc10[r]);
                atomicAdd(&agg[(size_t)i1 * 64 + 32 + mr], acc11[r]);
            }
        }
    }
}

// ---------------- K2 (two-phase): stream-reduce paired msg16 + mean + root + relu + gate ----------------
__global__ __launch_bounds__(256) void k2_red(
    const unsigned* __restrict__ msg16, const int* __restrict__ base,
    const int* __restrict__ deg,
    const float* __restrict__ x, const float* __restrict__ root,
    const float* __restrict__ conv_bias,
    unsigned short* __restrict__ hn16,
    const float* __restrict__ Wg, const float* __restrict__ bg,
    float* __restrict__ gate)
{
    __shared__ float sroot[16][64];
    int t = threadIdx.x;
    #pragma unroll
    for (int q = 0; q < 4; ++q) {
        int i = q * 256 + t;
        sroot[i >> 6][i & 63] = root[i];
    }
    __syncthreads();

    int n = blockIdx.x * 4 + (t >> 6);
    int l = t & 63;
    int mr = l & 31, so = l >> 5;
    int s = base[n];
    int e = s + deg[n];

    float alo = 0.f, ahi = 0.f;
    int sl = s + so;
    for (; sl + 2 < e; sl += 4) {
        unsigned u0 = msg16[(size_t)sl * 32 + mr];
        unsigned u1 = msg16[(size_t)(sl + 2) * 32 + mr];
        alo += __uint_as_float(u0 << 16) + __uint_as_float(u1 << 16);
        ahi += __uint_as_float(u0 & 0xFFFF0000u) + __uint_as_float(u1 & 0xFFFF0000u);
    }
    if (sl < e) {
        unsigned u = msg16[(size_t)sl * 32 + mr];
        alo += __uint_as_float(u << 16);
        ahi += __uint_as_float(u & 0xFFFF0000u);
    }
    alo += __shfl_xor(alo, 32);
    ahi += __shfl_xor(ahi, 32);
    float acc = (l < 32) ? alo : ahi;

    float inv = 1.0f / fmaxf((float)(e - s), 1.0f);
    float v = acc * inv + conv_bias[l];
    float xv = (l < 16) ? x[(size_t)n * NI + l] : 0.f;
    #pragma unroll
    for (int i = 0; i < 16; ++i)
        v = fmaf(__shfl(xv, i), sroot[i][l], v);
    v = fmaxf(v, 0.f);
    hn16[(size_t)n * 64 + l] = f2bf(v);

    float gv = v * Wg[l];
    #pragma unroll
    for (int off = 32; off; off >>= 1) gv += __shfl_xor(gv, off);
    if (l == 0) gate[n] = gv + bg[0];
}

// ---------------- K2 (fallback): mean + root + relu over agg ----------------
__global__ __launch_bounds__(256) void k2_node(
    const float* __restrict__ agg, const int* __restrict__ deg,
    const float* __restrict__ x, const float* __restrict__ root,
    const float* __restrict__ conv_bias,
    unsigned short* __restrict__ hn16,
    const float* __restrict__ Wg, const float* __restrict__ bg,
    float* __restrict__ gate)
{
    int t = threadIdx.x;
    int n = blockIdx.x * 4 + (t >> 6);
    int h = t & 63;
    float inv = 1.0f / fmaxf((float)deg[n], 1.0f);
    float v = agg[(size_t)n * 64 + h] * inv + conv_bias[h];
    const float* xp = x + (size_t)n * NI;
    #pragma unroll
    for (int i = 0; i < NI; ++i) v += xp[i] * root[i * 64 + h];
    v = fmaxf(v, 0.f);
    hn16[(size_t)n * 64 + h] = f2bf(v);
    float gv = v * Wg[h];
    #pragma unroll
    for (int off = 32; off; off >>= 1) gv += __shfl_xor(gv, off);
    if (h == 0) gate[n] = gv + bg[0];
}

// ---------------- K3: per-graph pooling + pg/sg precompute ----------------
__global__ __launch_bounds__(64) void k3_pool(
    const float* __restrict__ gate, const int* __restrict__ gs,
    const unsigned short* __restrict__ hn16, const float* __restrict__ pocket,
    const float* __restrict__ W_fc1, const float* __restrict__ b_fc1,
    const float* __restrict__ W_sp, const float* __restrict__ b_sp,
    float* __restrict__ pg, float* __restrict__ sg)
{
    int g = blockIdx.x;
    int lane = threadIdx.x;
    int s = gs[g];
    int e = gs[g + 1];

    float gcv = 0.f;
    if (e > s) {
        float m = -INFINITY;
        for (int n = s + lane; n < e; n += 64) m = fmaxf(m, gate[n]);
        #pragma unroll
        for (int off = 32; off; off >>= 1) m = fmaxf(m, __shfl_xor(m, off));
        float acc = 0.f, den = 0.f;
        int n = s;
        for (; n + 2 <= e; n += 2) {
            float e0 = expf(gate[n] - m);
            float e1 = expf(gate[n + 1] - m);
            float h0 = bf2f(hn16[(size_t)n * 64 + lane]);
            float h1 = bf2f(hn16[(size_t)(n + 1) * 64 + lane]);
            den += e0 + e1;
            acc = fmaf(e0, h0, acc);
            acc = fmaf(e1, h1, acc);
        }
        if (n < e) {
            float ev = expf(gate[n] - m);
            den += ev;
            acc = fmaf(ev, bf2f(hn16[(size_t)n * 64 + lane]), acc);
        }
        gcv = acc / den;
    }

    float sv = gcv * W_sp[lane];
    #pragma unroll
    for (int off = 32; off; off >>= 1) sv += __shfl_xor(sv, off);
    if (lane == 0) sg[g] = 1.f / (1.f + expf(-(sv + b_sp[0])));

    float pk = (lane < GFD) ? pocket[(size_t)g * GFD + lane] : 0.f;
    float pgv = b_fc1[lane];
    #pragma unroll 8
    for (int kk = 0; kk < 64; ++kk)
        pgv = fmaf(__shfl(gcv, kk), W_fc1[(64 + kk) * 64 + lane], pgv);
    #pragma unroll 8
    for (int kk = 0; kk < 32; ++kk)
        pgv = fmaf(__shfl(pk, kk), W_fc1[(128 + kk) * 64 + lane], pgv);
    pg[(size_t)g * 64 + lane] = pgv;
}

// ---------------- K4: MFMA head ----------------
__global__ __launch_bounds__(256, 4) void k4_mfma(
    const unsigned short* __restrict__ hn16, const int* __restrict__ batch,
    const float* __restrict__ pg, const float* __restrict__ sg,
    const unsigned short* __restrict__ W1aT, const unsigned short* __restrict__ W_npT,
    const float* __restrict__ b_np,
    float* __restrict__ out_np, float* __restrict__ out_stop)
{
    __shared__ __align__(16) float sF[4][32][FPAD];
    __shared__ int sB[128];

    const int t = threadIdx.x;
    const int wv = t >> 6, lane = t & 63;
    const int mr = lane & 31, half = lane >> 5;
    const int nb = blockIdx.x * 128;

    if (t < 128) {
        int n = nb + t;
        sB[t] = (n < NN) ? batch[n] : 0;
    }

    const int node = nb + wv * 32 + mr;

    f32x16 acc0, acc1;
    #pragma unroll
    for (int r = 0; r < 16; ++r) { acc0[r] = 0.f; acc1[r] = 0.f; }

    #pragma unroll
    for (int c = 0; c < 4; ++c) {
        short8v a;
        if (node < NN) {
            a = *(const short8v*)(hn16 + (size_t)node * 64 + c * 16 + half * 8);
        } else {
            #pragma unroll
            for (int q = 0; q < 8; ++q) a[q] = 0;
        }
        short8v b0 = *(const short8v*)(W1aT + (size_t)mr * 64        + c * 16 + half * 8);
        short8v b1 = *(const short8v*)(W1aT + (size_t)(mr + 32) * 64 + c * 16 + half * 8);
        acc0 = __builtin_amdgcn_mfma_f32_32x32x16_bf16(a, b0, acc0, 0, 0, 0);
        acc1 = __builtin_amdgcn_mfma_f32_32x32x16_bf16(a, b1, acc1, 0, 0, 0);
    }
    __syncthreads();

    #pragma unroll
    for (int r = 0; r < 16; ++r) {
        int row = (r & 3) + 8 * (r >> 2) + 4 * half;
        int g = sB[wv * 32 + row];
        float p0 = pg[(size_t)g * 64 + mr];
        float p1 = pg[(size_t)g * 64 + 32 + mr];
        sF[wv][row][mr]      = fmaxf(acc0[r] + p0, 0.f);
        sF[wv][row][32 + mr] = fmaxf(acc1[r] + p1, 0.f);
    }

    f32x16 acc2, acc3;
    #pragma unroll
    for (int r = 0; r < 16; ++r) { acc2[r] = 0.f; acc3[r] = 0.f; }

    #pragma unroll
    for (int c = 0; c < 4; ++c) {
        const float* fp = &sF[wv][mr][c * 16 + half * 8];
        float4 u0 = *(const float4*)(fp);
        float4 u1 = *(const float4*)(fp + 4);
        union { short8v v; unsigned u[4]; } A;
        A.u[0] = cvtpk(u0.x, u0.y); A.u[1] = cvtpk(u0.z, u0.w);
        A.u[2] = cvtpk(u1.x, u1.y); A.u[3] = cvtpk(u1.z, u1.w);
        short8v a = A.v;
        short8v b0 = *(const short8v*)(W_npT + (size_t)mr * 64        + c * 16 + half * 8);
        short8v b1 = *(const short8v*)(W_npT + (size_t)(mr + 32) * 64 + c * 16 + half * 8);
        acc2 = __builtin_amdgcn_mfma_f32_32x32x16_bf16(a, b0, acc2, 0, 0, 0);
        acc3 = __builtin_amdgcn_mfma_f32_32x32x16_bf16(a, b1, acc3, 0, 0, 0);
    }

    float bn1 = b_np[mr];
    float bn2 = (mr < 8) ? b_np[32 + mr] : 0.f;

    #pragma unroll
    for (int r = 0; r < 16; ++r) {
        int row = (r & 3) + 8 * (r >> 2) + 4 * half;
        int n = nb + wv * 32 + row;
        float v1 = acc2[r] + bn1;
        float v2 = acc3[r] + bn2;
        float m = (mr < 8) ? fmaxf(v1, v2) : v1;
        #pragma unroll
        for (int off = 16; off; off >>= 1) m = fmaxf(m, __shfl_xor(m, off));
        float s = expf(v1 - m) + ((mr < 8) ? expf(v2 - m) : 0.f);
        #pragma unroll
        for (int off = 16; off; off >>= 1) s += __shfl_xor(s, off);
        float ls = m + logf(s);
        if (n < NN) {
            out_np[(size_t)n * CC + mr] = v1 - ls;
            if (mr < 8) out_np[(size_t)n * CC + 32 + mr] = v2 - ls;
            if (mr == 0) out_stop[n] = sg[sB[wv * 32 + row]];
        }
    }
}

extern "C" void kernel_launch(void* const* d_in, const int* in_sizes, int n_in,
                              void* d_out, int out_size, void* d_ws, size_t ws_size,
                              hipStream_t stream)
{
    (void)in_sizes; (void)n_in; (void)out_size;
    const float* x        = (const float*)d_in[0];
    const int*   ei       = (const int*)d_in[1];
    const float* ea       = (const float*)d_in[2];
    const int*   batch    = (const int*)d_in[3];
    const float* pocket   = (const float*)d_in[4];
    const float* W_e1     = (const float*)d_in[5];
    const float* b_e1     = (const float*)d_in[6];
    const float* W_e2     = (const float*)d_in[7];
    const float* b_e2     = (const float*)d_in[8];
    const float* root     = (const float*)d_in[9];
    const float* conv_b   = (const float*)d_in[10];
    const float* Wg       = (const float*)d_in[11];
    const float* bg       = (const float*)d_in[12];
    const float* W_fc1    = (const float*)d_in[13];
    const float* b_fc1    = (const float*)d_in[14];
    const float* W_np     = (const float*)d_in[15];
    const float* b_np     = (const float*)d_in[16];
    const float* W_sp     = (const float*)d_in[17];
    const float* b_sp     = (const float*)d_in[18];

    char* wsb = (char*)d_ws;
    float* agg    = (float*)wsb;                         // NN*64 (atomic fallback only)
    int*   base   = (int*)(agg + (size_t)NN * 64);       // NN
    int*   gcur   = base + NN;                           // 1 (+pad)
    int*   cursor = gcur + 4;                            // NN (degree counts after kE)
    int*   rank   = cursor + NN;                         // EE
    int*   gs     = rank + EE;                           // GG+1
    float* gate   = (float*)(gs + GG + 4);               // NN
    float* pg     = gate + NN;                           // GG*64
    float* sg     = pg + (size_t)GG * 64;                // GG
    unsigned short* hn16  = (unsigned short*)(sg + GG);  // NN*64 u16
    unsigned short* W2c   = hn16 + (size_t)NN * 64;      // W2SZ
    unsigned short* W1aT  = W2c + W2SZ;                  // 4096
    unsigned short* W_npT = W1aT + 4096;                 // 4096
    unsigned short* W1e   = W_npT + 4096;                // 512
    size_t head = (size_t)((char*)(W1e + 512) - wsb);
    size_t msg_off = (head + 255) & ~(size_t)255;
    unsigned* msg16 = (unsigned*)(wsb + msg_off);        // EE*32 u32
    size_t need = msg_off + (size_t)EE * 32 * sizeof(unsigned);
    const bool twophase = (ws_size >= need);

    k0_prep<<<(W2SZ + 8705 + NN + 255) / 256, 256, 0, stream>>>(
        W_e2, b_e2, W_fc1, W_np, W_e1, W2c, W1aT, W_npT, W1e, cursor, gcur);

    kE_local<<<(EE + 255) / 256, 256, 0, stream>>>(ei, cursor, rank);
    kB_scan<<<NBLK, 256, 0, stream>>>(cursor, base, gcur);
    kG_bounds<<<(NN + 255) / 256, 256, 0, stream>>>(batch, gs);

    if (twophase) {
        k1_mfma<true><<<(EE + 255) / 256, 256, 0, stream>>>(
            x, ei, ea, W1e, b_e1, W2c, rank, base, msg16, agg);
        k2_red<<<NN / 4, 256, 0, stream>>>(msg16, base, cursor, x, root, conv_b,
                                           hn16, Wg, bg, gate);
    } else {
        hipMemsetAsync(agg, 0, (size_t)NN * 64 * sizeof(float), stream);
        k1_mfma<false><<<(EE + 255) / 256, 256, 0, stream>>>(
            x, ei, ea, W1e, b_e1, W2c, rank, base, msg16, agg);
        k2_node<<<NN / 4, 256, 0, stream>>>(agg, cursor, x, root, conv_b,
                                            hn16, Wg, bg, gate);
    }

    k3_pool<<<GG, 64, 0, stream>>>(gate, gs, hn16, pocket, W_fc1, b_fc1, W_sp, b_sp, pg, sg);

    float* out_np   = (float*)d_out;
    float* out_stop = out_np + (size_t)NN * CC;
    k4_mfma<<<(NN + 127) / 128, 256, 0, stream>>>(hn16, batch, pg, sg, W1aT, W_npT, b_np,
                                                  out_np, out_stop);
}